// Round 1
// baseline (16.111 us; speedup 1.0000x reference)
//
#include <hip/hip_runtime.h>

#define EPS 1e-6f

__global__ __launch_bounds__(256) void LinearObjectness_kernel(
    const float* __restrict__ enc,
    const float* __restrict__ gamma,
    const float* __restrict__ w,
    const float* __restrict__ bias,
    float* __restrict__ out,
    int N_IMG, int S, int D)
{
    const int row = blockIdx.x;              // 0 .. B*N_IMG-1
    const int b   = row / N_IMG;
    const int n   = row % N_IMG;
    const float* __restrict__ x = enc + ((size_t)b * S + n) * (size_t)D;

    const int t = threadIdx.x;

    float sumsq = 0.f;
    float dot   = 0.f;

    // D elements, 256 threads, float4 per thread per 1024-element chunk.
    for (int base = 0; base < D; base += 1024) {
        const int idx = base + t * 4;
        const float4 xv = *reinterpret_cast<const float4*>(x + idx);
        const float4 gv = *reinterpret_cast<const float4*>(gamma + idx);
        const float4 wv = *reinterpret_cast<const float4*>(w + idx);
        sumsq += xv.x * xv.x + xv.y * xv.y + xv.z * xv.z + xv.w * xv.w;
        dot   += xv.x * gv.x * wv.x + xv.y * gv.y * wv.y
               + xv.z * gv.z * wv.z + xv.w * gv.w * wv.w;
    }

    // 64-lane wave butterfly reduce
    #pragma unroll
    for (int o = 32; o > 0; o >>= 1) {
        sumsq += __shfl_down(sumsq, o, 64);
        dot   += __shfl_down(dot,   o, 64);
    }

    __shared__ float s_sq[4];
    __shared__ float s_dot[4];
    const int wid  = t >> 6;
    const int lane = t & 63;
    if (lane == 0) { s_sq[wid] = sumsq; s_dot[wid] = dot; }
    __syncthreads();

    if (t == 0) {
        const float ss  = s_sq[0] + s_sq[1] + s_sq[2] + s_sq[3];
        const float dd  = s_dot[0] + s_dot[1] + s_dot[2] + s_dot[3];
        const float inv = rsqrtf(ss / (float)D + EPS);
        out[row] = dd * inv + bias[0];
    }
}

extern "C" void kernel_launch(void* const* d_in, const int* in_sizes, int n_in,
                              void* d_out, int out_size, void* d_ws, size_t ws_size,
                              hipStream_t stream) {
    const float* enc   = (const float*)d_in[0];   // (B, S, D)
    // d_in[1] objectness: unused by reference math
    // d_in[2] boxes: only shape matters
    const float* gamma = (const float*)d_in[3];   // (D,)
    const float* w     = (const float*)d_in[4];   // (D,)
    const float* bias  = (const float*)d_in[5];   // scalar
    float* out         = (float*)d_out;           // (B, N_IMG)

    const int D     = in_sizes[3];                // 2048
    const int B     = 4;                          // fixed by harness setup
    const int BN    = in_sizes[1];                // B * N_IMG = 8192
    const int N_IMG = BN / B;                     // 2048
    const int S     = in_sizes[0] / (B * D);      // 4096

    LinearObjectness_kernel<<<BN, 256, 0, stream>>>(enc, gamma, w, bias, out,
                                                    N_IMG, S, D);
}

// Round 2
// 15.797 us; speedup vs baseline: 1.0199x; 1.0199x over previous
//
#include <hip/hip_runtime.h>

#define EPS 1e-6f

// Wave-per-row fused RMSNorm + dot. D known at compile time -> full unroll,
// deep ILP, no LDS, no __syncthreads.
template<int D>
__global__ __launch_bounds__(256, 4) void lo_kernel(
    const float* __restrict__ enc,
    const float* __restrict__ gamma,
    const float* __restrict__ w,
    const float* __restrict__ bias,
    float* __restrict__ out,
    int N_IMG, int S, int n_rows)
{
    const int lane = threadIdx.x & 63;
    const int row  = blockIdx.x * 4 + (threadIdx.x >> 6);
    if (row >= n_rows) return;

    const int b = row / N_IMG;
    const int n = row % N_IMG;
    const float* __restrict__ x = enc + ((size_t)b * S + n) * (size_t)D;

    constexpr int ITER = D / 256;   // 64 lanes * float4 per iter

    float sumsq = 0.f, dot = 0.f;
    #pragma unroll
    for (int i = 0; i < ITER; ++i) {
        const int idx = i * 256 + lane * 4;
        const float4 xv = *reinterpret_cast<const float4*>(x + idx);
        const float4 gv = *reinterpret_cast<const float4*>(gamma + idx);
        const float4 wv = *reinterpret_cast<const float4*>(w + idx);
        sumsq = fmaf(xv.x, xv.x, fmaf(xv.y, xv.y, fmaf(xv.z, xv.z, fmaf(xv.w, xv.w, sumsq))));
        dot  = fmaf(xv.x * gv.x, wv.x,
               fmaf(xv.y * gv.y, wv.y,
               fmaf(xv.z * gv.z, wv.z,
               fmaf(xv.w * gv.w, wv.w, dot))));
    }

    #pragma unroll
    for (int o = 32; o > 0; o >>= 1) {
        sumsq += __shfl_xor(sumsq, o, 64);
        dot   += __shfl_xor(dot,   o, 64);
    }

    if (lane == 0) {
        const float inv = rsqrtf(sumsq * (1.0f / (float)D) + EPS);
        out[row] = dot * inv + bias[0];
    }
}

// Generic fallback (runtime D), block-per-row.
__global__ __launch_bounds__(256) void lo_kernel_generic(
    const float* __restrict__ enc,
    const float* __restrict__ gamma,
    const float* __restrict__ w,
    const float* __restrict__ bias,
    float* __restrict__ out,
    int N_IMG, int S, int D)
{
    const int row = blockIdx.x;
    const int b   = row / N_IMG;
    const int n   = row % N_IMG;
    const float* __restrict__ x = enc + ((size_t)b * S + n) * (size_t)D;
    const int t = threadIdx.x;

    float sumsq = 0.f, dot = 0.f;
    for (int d = t; d < D; d += 256) {
        const float xv = x[d];
        sumsq = fmaf(xv, xv, sumsq);
        dot   = fmaf(xv * gamma[d], w[d], dot);
    }
    #pragma unroll
    for (int o = 32; o > 0; o >>= 1) {
        sumsq += __shfl_xor(sumsq, o, 64);
        dot   += __shfl_xor(dot,   o, 64);
    }
    __shared__ float s_sq[4], s_dot[4];
    const int wid = t >> 6, lane = t & 63;
    if (lane == 0) { s_sq[wid] = sumsq; s_dot[wid] = dot; }
    __syncthreads();
    if (t == 0) {
        float ss = s_sq[0] + s_sq[1] + s_sq[2] + s_sq[3];
        float dd = s_dot[0] + s_dot[1] + s_dot[2] + s_dot[3];
        out[row] = dd * rsqrtf(ss / (float)D + EPS) + bias[0];
    }
}

extern "C" void kernel_launch(void* const* d_in, const int* in_sizes, int n_in,
                              void* d_out, int out_size, void* d_ws, size_t ws_size,
                              hipStream_t stream) {
    const float* enc   = (const float*)d_in[0];   // (B, S, D)
    const float* gamma = (const float*)d_in[3];   // (D,)
    const float* w     = (const float*)d_in[4];   // (D,)
    const float* bias  = (const float*)d_in[5];   // scalar
    float* out         = (float*)d_out;           // (B, N_IMG)

    const int D      = in_sizes[3];               // 2048
    const int B      = 4;
    const int BN     = in_sizes[1];               // B * N_IMG
    const int N_IMG  = BN / B;
    const int S      = in_sizes[0] / (B * D);
    const int n_rows = out_size;                  // B * N_IMG

    if (D == 2048) {
        const int blocks = (n_rows + 3) / 4;      // 4 rows (waves) per block
        lo_kernel<2048><<<blocks, 256, 0, stream>>>(enc, gamma, w, bias, out,
                                                    N_IMG, S, n_rows);
    } else {
        lo_kernel_generic<<<n_rows, 256, 0, stream>>>(enc, gamma, w, bias, out,
                                                      N_IMG, S, D);
    }
}

// Round 3
// 15.686 us; speedup vs baseline: 1.0271x; 1.0070x over previous
//
#include <hip/hip_runtime.h>

#define EPS 1e-6f

using f4 = __attribute__((ext_vector_type(4))) float;

// Fused RMSNorm + weighted-dot, wave-per-2-rows.
// gamma*w precomputed into 32 VGPRs per wave; hot loop reads ONLY x
// (8x global_load_dwordx4 nt per row), 4 independent FMA chains via
// vector accumulators.
template<int D, int R>
__global__ __launch_bounds__(256, 4) void lo_kernel(
    const float* __restrict__ enc,
    const float* __restrict__ gamma,
    const float* __restrict__ w,
    const float* __restrict__ bias,
    float* __restrict__ out,
    int N_IMG, int S, int n_rows)
{
    constexpr int ITER = D / 256;           // 64 lanes * 4 floats
    const int lane = threadIdx.x & 63;
    const int wid  = threadIdx.x >> 6;
    const int wave = blockIdx.x * 4 + wid;
    const int row0 = wave * R;
    if (row0 >= n_rows) return;

    const int col = lane * 4;

    // gamma*w -> registers, once per wave (L2-resident reads)
    f4 gw[ITER];
    #pragma unroll
    for (int i = 0; i < ITER; ++i) {
        const int idx = i * 256 + col;
        const f4 gv = *reinterpret_cast<const f4*>(gamma + idx);
        const f4 wv = *reinterpret_cast<const f4*>(w + idx);
        gw[i] = gv * wv;
    }

    const float bb = bias[0];

    #pragma unroll
    for (int r = 0; r < R; ++r) {
        const int row = row0 + r;
        if (row >= n_rows) break;
        const int b = row / N_IMG;
        const int n = row - b * N_IMG;
        const float* __restrict__ x = enc + ((size_t)b * S + n) * (size_t)D;

        f4 sq = {0.f, 0.f, 0.f, 0.f};
        f4 dt = {0.f, 0.f, 0.f, 0.f};
        #pragma unroll
        for (int i = 0; i < ITER; ++i) {
            const f4 xv = __builtin_nontemporal_load(
                reinterpret_cast<const f4*>(x + i * 256 + col));
            sq += xv * xv;
            dt += xv * gw[i];
        }

        float ssq = sq.x + sq.y + sq.z + sq.w;
        float ddt = dt.x + dt.y + dt.z + dt.w;
        #pragma unroll
        for (int o = 32; o > 0; o >>= 1) {
            ssq += __shfl_xor(ssq, o, 64);
            ddt += __shfl_xor(ddt, o, 64);
        }
        if (lane == 0) {
            out[row] = ddt * rsqrtf(ssq * (1.0f / (float)D) + EPS) + bb;
        }
    }
}

// Generic fallback (runtime D), block-per-row.
__global__ __launch_bounds__(256) void lo_kernel_generic(
    const float* __restrict__ enc,
    const float* __restrict__ gamma,
    const float* __restrict__ w,
    const float* __restrict__ bias,
    float* __restrict__ out,
    int N_IMG, int S, int D)
{
    const int row = blockIdx.x;
    const int b   = row / N_IMG;
    const int n   = row % N_IMG;
    const float* __restrict__ x = enc + ((size_t)b * S + n) * (size_t)D;
    const int t = threadIdx.x;

    float sumsq = 0.f, dot = 0.f;
    for (int d = t; d < D; d += 256) {
        const float xv = x[d];
        sumsq = fmaf(xv, xv, sumsq);
        dot   = fmaf(xv * gamma[d], w[d], dot);
    }
    #pragma unroll
    for (int o = 32; o > 0; o >>= 1) {
        sumsq += __shfl_xor(sumsq, o, 64);
        dot   += __shfl_xor(dot,   o, 64);
    }
    __shared__ float s_sq[4], s_dot[4];
    const int wid = t >> 6, lane = t & 63;
    if (lane == 0) { s_sq[wid] = sumsq; s_dot[wid] = dot; }
    __syncthreads();
    if (t == 0) {
        float ss = s_sq[0] + s_sq[1] + s_sq[2] + s_sq[3];
        float dd = s_dot[0] + s_dot[1] + s_dot[2] + s_dot[3];
        out[row] = dd * rsqrtf(ss / (float)D + EPS) + bias[0];
    }
}

extern "C" void kernel_launch(void* const* d_in, const int* in_sizes, int n_in,
                              void* d_out, int out_size, void* d_ws, size_t ws_size,
                              hipStream_t stream) {
    const float* enc   = (const float*)d_in[0];   // (B, S, D)
    const float* gamma = (const float*)d_in[3];   // (D,)
    const float* w     = (const float*)d_in[4];   // (D,)
    const float* bias  = (const float*)d_in[5];   // scalar
    float* out         = (float*)d_out;           // (B, N_IMG)

    const int D      = in_sizes[3];               // 2048
    const int B      = 4;
    const int BN     = in_sizes[1];               // B * N_IMG
    const int N_IMG  = BN / B;
    const int S      = in_sizes[0] / (B * D);
    const int n_rows = out_size;                  // B * N_IMG

    if (D == 2048) {
        constexpr int R = 2;
        const int waves  = (n_rows + R - 1) / R;  // 4096
        const int blocks = (waves + 3) / 4;       // 1024
        lo_kernel<2048, R><<<blocks, 256, 0, stream>>>(enc, gamma, w, bias, out,
                                                       N_IMG, S, n_rows);
    } else {
        lo_kernel_generic<<<n_rows, 256, 0, stream>>>(enc, gamma, w, bias, out,
                                                      N_IMG, S, D);
    }
}